// Round 11
// baseline (149.986 us; speedup 1.0000x reference)
//
#include <hip/hip_runtime.h>
#include <cstdint>

typedef float  f32x4  __attribute__((ext_vector_type(4)));
typedef short  short8 __attribute__((ext_vector_type(8)));
typedef _Float16 half4 __attribute__((ext_vector_type(4)));

// ---------- helpers ----------
__device__ __forceinline__ unsigned short f2bf(float f) {
    unsigned u = __builtin_bit_cast(unsigned, f);
    u += 0x7FFFu + ((u >> 16) & 1u);   // RNE
    return (unsigned short)(u >> 16);
}

// ---------- kernel 1: weights fp32 -> bf16 (3 x 256 x 256) ----------
__global__ void wconv_kernel(const float* __restrict__ wq,
                             const float* __restrict__ wk,
                             const float* __restrict__ wv,
                             unsigned short* __restrict__ Wb) {
    int p = blockIdx.x >> 8;                       // 0..2
    int i = ((blockIdx.x & 255) << 8) + threadIdx.x; // 0..65535
    const float* src = (p == 0) ? wq : ((p == 1) ? wk : wv);
    Wb[(p << 16) + i] = f2bf(src[i]);
}

// ---------- kernel 2: build X0 [B][S][256] bf16 ----------
__global__ void build_x0_kernel(const float* __restrict__ x,
                                unsigned short* __restrict__ X0) {
    __shared__ float tile[32][33];
    int b  = blockIdx.z;
    int ct = blockIdx.y;     // 0..7  (32 channels each)
    int st = blockIdx.x;     // 0..31 (32 s each)
    int tid = threadIdx.x;
    int lo = tid & 31, hi = tid >> 5;   // 8 rows per pass

    if (ct < 7) {
        #pragma unroll
        for (int r = 0; r < 4; ++r) {
            int c = hi + 8 * r;
            tile[c][lo] = x[((b * 224 + ct * 32 + c) << 10) + st * 32 + lo];
        }
        __syncthreads();
        #pragma unroll
        for (int r = 0; r < 4; ++r) {
            int s_loc = hi + 8 * r;
            X0[(((b << 10) + st * 32 + s_loc) << 8) + ct * 32 + lo] = f2bf(tile[lo][s_loc]);
        }
    } else {
        #pragma unroll
        for (int r = 0; r < 4; ++r) {
            int s_loc = hi + 8 * r;
            int s = st * 32 + s_loc;
            int h = s >> 5, w = s & 31;
            int ch = lo;  // 0..31 -> pe channel
            int i = (ch < 16) ? (ch * 32 + h) : ((ch - 16) * 32 + w);
            int l = i >> 4, e = i & 15;
            float val = 0.f;
            if (l > 0) {
                float ang = (float)l * powf(10000.f, -(float)(e >> 1) * 0.125f);
                val = (e & 1) ? cosf(ang) : sinf(ang);
            }
            X0[(((b << 10) + s) << 8) + 224 + ch] = f2bf(val);
        }
    }
}

// ---------- kernel 3: QKV projection, LDS-staged ----------
__global__ __launch_bounds__(256) void proj_kernel(
        const unsigned short* __restrict__ X0,
        const unsigned short* __restrict__ Wb,
        const float* __restrict__ bq, const float* __restrict__ bk,
        const float* __restrict__ bv,
        unsigned short* __restrict__ Q, unsigned short* __restrict__ K,
        _Float16* __restrict__ V) {
    __shared__ __align__(16) char Xlds[32768];   // 64 s-rows x 512B
    __shared__ __align__(16) char Wlds[32768];   // 64 o-rows x 512B

    int pb = blockIdx.z; int proj = pb >> 5; int b = pb & 31;
    int tid = threadIdx.x; int w = tid >> 6; int l = tid & 63;
    int g = l >> 4, c = l & 15;
    int sb = blockIdx.x * 64;           // s-tile base
    int o0 = blockIdx.y * 64;           // o-tile base
    const unsigned short* Wp = Wb + (proj << 16);
    const float* bias = (proj == 0) ? bq : ((proj == 1) ? bk : bv);

    // ---- stage X0 tile: 2048 16B chunks, coalesced, swizzled ----
    const unsigned short* Xg = &X0[((b << 10) + sb) << 8];
    #pragma unroll
    for (int p = 0; p < 8; ++p) {
        int ch = p * 256 + tid;
        int row = ch >> 5, cc = ch & 31;
        short8 v = *(const short8*)&Xg[(row << 8) + cc * 8];
        *(short8*)&Xlds[((ch & ~31) | (cc ^ (row & 7))) << 4] = v;
    }
    // ---- stage W tile: 2048 16B chunks ----
    const unsigned short* Wg = &Wp[o0 << 8];
    #pragma unroll
    for (int p = 0; p < 8; ++p) {
        int ch = p * 256 + tid;
        int row = ch >> 5, cc = ch & 31;
        short8 v = *(const short8*)&Wg[(row << 8) + cc * 8];
        *(short8*)&Wlds[((ch & ~31) | (cc ^ (row & 7))) << 4] = v;
    }
    __syncthreads();

    // ---- A fragments (this wave's 16 s-rows) into registers ----
    int s0 = sb + w * 16;
    const char* abase = &Xlds[(w * 16 + c) * 512];
    short8 af[8];
    #pragma unroll
    for (int kk = 0; kk < 8; ++kk)
        af[kk] = *(const short8*)&abase[((kk * 4 + g) ^ (c & 7)) << 4];

    f32x4 acc[4];
    #pragma unroll
    for (int ot = 0; ot < 4; ++ot) acc[ot] = (f32x4){0.f, 0.f, 0.f, 0.f};

    __builtin_amdgcn_s_setprio(1);
    #pragma unroll
    for (int ot = 0; ot < 4; ++ot) {
        const char* bbase = &Wlds[(ot * 16 + c) * 512];
        #pragma unroll
        for (int kk = 0; kk < 8; ++kk) {
            short8 bfr = *(const short8*)&bbase[((kk * 4 + g) ^ (c & 7)) << 4];
            acc[ot] = __builtin_amdgcn_mfma_f32_16x16x32_bf16(af[kk], bfr, acc[ot], 0, 0, 0);
        }
    }
    __builtin_amdgcn_s_setprio(0);

    #pragma unroll
    for (int ot = 0; ot < 4; ++ot) {
        int o = o0 + ot * 16 + c;
        float bb = bias[o];
        if (proj < 2) {
            unsigned short* dst = (proj == 0) ? Q : K;
            #pragma unroll
            for (int r = 0; r < 4; ++r) {
                float v = fmaxf(acc[ot][r] + bb, 0.f);
                int s = s0 + 4 * g + r;
                dst[(((b << 10) + s) << 8) + o] = f2bf(v);
            }
        } else {
            half4 hv;
            #pragma unroll
            for (int r = 0; r < 4; ++r)
                hv[r] = (_Float16)fmaxf(acc[ot][r] + bb, 0.f);
            *(half4*)&V[(((b << 8) + o) << 10) + s0 + 4 * g] = hv;
        }
    }
}

// ---------- kernel 4: causal attention ----------
// 512 blocks x 256 threads (4 waves x 16 q-rows = 64-row q-tile).
// t-tile = 16; K (8KB, XOR row&7 on 16B chunks) + V (8KB linear, 32B rows)
// double-buffered (32KB total) -> 3 blocks/CU (launch_bounds 256,3).
// Staged via global_load_lds; pipeline: [vmcnt(0)+s_barrier] -> stage(t+1)
// -> compute(t). Steady-state softmax has ZERO cross-lane ops: per-lane
// partial lsum (row-summed once in epilogue) + defer-max fast path.
__global__ __launch_bounds__(256, 3) void attn_kernel(
        const unsigned short* __restrict__ Q,
        const unsigned short* __restrict__ K,
        const _Float16* __restrict__ V,
        float* __restrict__ out) {
    __shared__ __align__(16) char Klds[2][8192];   // 16 t-rows x 512B
    __shared__ __align__(16) char Vlds[2][8192];   // 256 v-rows x 32B

    int bid = blockIdx.x;
    int xcd  = bid & 7;
    int qv   = (bid >> 3) & 7;
    int bhi  = (bid >> 6) & 3;
    int hf   = bid >> 8;
    int b  = (bhi << 3) | xcd;
    int qt = hf ? qv : (15 - qv);       // 0..15, 64-row q-tile

    int tid = threadIdx.x; int w = tid >> 6; int l = tid & 63;
    int g = l >> 4, c = l & 15;
    int s0 = (qt << 6) + (w << 4);      // this wave's 16 q-rows

    // ---- Q fragments ----
    short8 qf[8];
    #pragma unroll
    for (int kk = 0; kk < 8; ++kk)
        qf[kk] = *(const short8*)&Q[(((b << 10) + s0 + c) << 8) + kk * 32 + g * 8];

    float m = -1e30f, lsum = 0.f;       // lsum: PER-LANE partial (4 t-cols)
    f32x4 acc[16];
    #pragma unroll
    for (int i = 0; i < 16; ++i) acc[i] = (f32x4){0.f, 0.f, 0.f, 0.f};

    const unsigned short* Kb_ = &K[(size_t)b << 18];
    const _Float16*       Vb_ = &V[(size_t)b << 18];

    int nt = (qt + 1) << 2;             // 16-wide t-tiles
    int dt = (qt << 2) + w;             // this wave's diagonal t-tile

    // stage tile t into buffer bufi: 256 threads x (2 K + 2 V) chunks
    auto stage = [&](int t, int bufi) {
        int t0 = t << 4;
        #pragma unroll
        for (int j = 0; j < 2; ++j) {
            int ch = (j << 8) + tid;            // 0..511
            int trow = ch >> 5;                 // 0..15
            int cl = (ch & 31) ^ (trow & 7);
            __builtin_amdgcn_global_load_lds(
                (const unsigned int*)&Kb_[((t0 + trow) << 8) + cl * 8],
                (unsigned int*)(Klds[bufi] + ((j << 8) + (w << 6)) * 16), 16, 0, 0);
        }
        #pragma unroll
        for (int j = 0; j < 2; ++j) {
            int ch = (j << 8) + tid;            // 0..511
            int v = ch >> 1;                    // 0..255
            int half = ch & 1;
            __builtin_amdgcn_global_load_lds(
                (const unsigned int*)&Vb_[(v << 10) + t0 + half * 8],
                (unsigned int*)(Vlds[bufi] + ((j << 8) + (w << 6)) * 16), 16, 0, 0);
        }
    };

    stage(0, 0);

    for (int t = 0; t < nt; ++t) {
        asm volatile("s_waitcnt vmcnt(0)\n\ts_barrier" ::: "memory");
        if (t + 1 < nt) stage(t + 1, (t + 1) & 1);   // overlap with compute(t)
        if (t > dt) continue;                        // done; keep barrier cadence

        const char* Kl = Klds[t & 1];
        const char* Vl = Vlds[t & 1];
        // ---- QK^T from LDS (16x16x32, 2 chains) ----
        f32x4 sc0 = {0.f,0.f,0.f,0.f}, sc1 = {0.f,0.f,0.f,0.f};
        const char* kbase = &Kl[c * 512];
        __builtin_amdgcn_s_setprio(1);
        #pragma unroll
        for (int kk = 0; kk < 8; kk += 2) {
            short8 a0 = *(const short8*)&kbase[(((kk * 4 + g)       ^ (c & 7)) << 4)];
            short8 a1 = *(const short8*)&kbase[((((kk + 1) * 4 + g) ^ (c & 7)) << 4)];
            sc0 = __builtin_amdgcn_mfma_f32_16x16x32_bf16(a0, qf[kk], sc0, 0, 0, 0);
            sc1 = __builtin_amdgcn_mfma_f32_16x16x32_bf16(a1, qf[kk + 1], sc1, 0, 0, 0);
        }
        __builtin_amdgcn_s_setprio(0);
        // ---- V fragments (linear rows of 32B; issued before softmax) ----
        half4 vf[16];
        #pragma unroll
        for (int vt = 0; vt < 16; ++vt)
            vf[vt] = *(const half4*)&Vl[((vt * 16 + c) << 5) + g * 8];
        // ---- scale + diagonal mask ----
        float sv[4];
        #pragma unroll
        for (int r = 0; r < 4; ++r) sv[r] = (sc0[r] + sc1[r]) * 0.0625f;
        if (t == dt) {
            #pragma unroll
            for (int r = 0; r < 4; ++r)
                if (4 * g + r > c) sv[r] = -1e30f;
        }
        // ---- softmax: shuffle-free fast path ----
        float tm = fmaxf(fmaxf(sv[0], sv[1]), fmaxf(sv[2], sv[3]));
        if (!__all((int)(tm <= m + 8.f))) {          // rare slow path
            float tr = fmaxf(tm, __shfl_xor(tm, 16));
            tr = fmaxf(tr, __shfl_xor(tr, 32));
            float mnew = fmaxf(m, tr);
            float alpha = __expf(m - mnew);
            m = mnew;
            lsum *= alpha;
            #pragma unroll
            for (int i = 0; i < 16; ++i) acc[i] *= alpha;
        }
        float p[4];
        #pragma unroll
        for (int r = 0; r < 4; ++r) { p[r] = __expf(sv[r] - m); lsum += p[r]; }
        half4 pb;
        #pragma unroll
        for (int r = 0; r < 4; ++r) pb[r] = (_Float16)p[r];
        // ---- PV (16x16x16 f16) ----
        __builtin_amdgcn_s_setprio(1);
        #pragma unroll
        for (int vt = 0; vt < 16; ++vt)
            acc[vt] = __builtin_amdgcn_mfma_f32_16x16x16f16(vf[vt], pb, acc[vt], 0, 0, 0);
        __builtin_amdgcn_s_setprio(0);
    }

    // ---- epilogue: row-sum of lsum (the only softmax shuffles) ----
    lsum += __shfl_xor(lsum, 16);
    lsum += __shfl_xor(lsum, 32);
    float rl = 1.f / lsum;
    #pragma unroll
    for (int vt = 0; vt < 16; ++vt) {
        #pragma unroll
        for (int r = 0; r < 4; ++r)
            out[(((b << 8) + vt * 16 + 4 * g + r) << 10) + s0 + c] = acc[vt][r] * rl;
    }
}

// ---------- launcher ----------
extern "C" void kernel_launch(void* const* d_in, const int* in_sizes, int n_in,
                              void* d_out, int out_size, void* d_ws, size_t ws_size,
                              hipStream_t stream) {
    const float* x  = (const float*)d_in[0];
    const float* wq = (const float*)d_in[1];
    const float* bq = (const float*)d_in[2];
    const float* wk = (const float*)d_in[3];
    const float* bk = (const float*)d_in[4];
    const float* wv = (const float*)d_in[5];
    const float* bv = (const float*)d_in[6];
    float* out = (float*)d_out;

    char* ws = (char*)d_ws;
    unsigned short* Wb = (unsigned short*)ws;                       // 393,216 B
    unsigned short* X0 = (unsigned short*)(ws + 393216);            // 16,777,216 B
    unsigned short* Qb = (unsigned short*)(ws + 393216 + 16777216);
    unsigned short* Kb = (unsigned short*)(ws + 393216 + 2 * 16777216);
    _Float16*       Vb = (_Float16*)     (ws + 393216 + 3 * 16777216);

    wconv_kernel<<<768, 256, 0, stream>>>(wq, wk, wv, Wb);
    build_x0_kernel<<<dim3(32, 8, 32), 256, 0, stream>>>(x, X0);
    proj_kernel<<<dim3(16, 4, 96), 256, 0, stream>>>(X0, Wb, bq, bk, bv, Qb, Kb, Vb);
    attn_kernel<<<512, 256, 0, stream>>>(Qb, Kb, Vb, out);
}